// Round 2
// baseline (346.116 us; speedup 1.0000x reference)
//
#include <hip/hip_runtime.h>
#include <math.h>

#define BATCH    16384
#define MAZE_LEN 3844
#define NCHUNK   961            // MAZE_LEN / 4 float4-chunks per row (exact)
#define RPB      4              // rows per block
#define NBLK1    (BATCH / RPB)  // 4096 blocks -> 16 queued/CU, backfill
#define NTERMS   120.0f         // chain has 120 multiplicands (col 3721 twice)

// Math: with p=0, and_f is additive under u(x)=1/x-1, so per row
//   S = sum_i w_i*(1/x_i) - 120;  -log(clamp(1/(1+S), e^-90)) = min(log1p(S), 90)
// where w is the per-column use-count (0/1/2; col 3721 appears twice).
//
// R6: R5's stream ran ~2 TB/s: 36 VGPRs of cached weights + per-row
// load->wait->shuffle serialization cut occupancy to ~16 waves/CU and MLP to
// ~4 loads/thread. This version: weights re-read per k-slice from the
// L1-resident 16KB constant table (frees 32 VGPRs), bias via 2 VALU ops,
// SGPR-uniform row bases (saddr loads, ~1 VGPR addressing), 16 independent
// row-loads per thread all issued before consumption, launch_bounds(256,8)
// to force <=64 VGPR => 32 waves/CU. Reduction happens once, off the load path.

struct WTab { float w[1024][4]; };   // 16 KB, padded chunks 961..1023 are zero

static constexpr WTab make_w() {
    WTab t{};
    int W[MAZE_LEN] = {};
    W[4 * 1 + 124 * 0 + 2]  += 1;    // IDX_A = 6
    W[4 * 29 + 124 * 30 + 3] += 1;   // IDX_B = 3839
    for (int i = 0; i < 31; ++i) { W[124 * i + 1] += 1; W[124 * i + 121] += 1; }
    for (int i = 0; i < 28; ++i) { W[4 * (i + 2) + 1] += 1; W[4 * i + 3721] += 1; }
    // NOTE: 124*30+1 == 4*0+3721 == 3721 -> weight 2 there. Total weight = 120.
    for (int c = 0; c < NCHUNK; ++c)
        for (int j = 0; j < 4; ++j) t.w[c][j] = (float)W[4 * c + j];
    return t;
}

__constant__ WTab c_w = make_w();

// Per element: term = w * rcp(x + B), B = 1e30 iff w==0.
//   - unused elem, any x (incl. 0): 0 * 1e-30 = exactly 0  (no 0*inf NaN)
//   - used elem, x==0: w * inf -> log1p(inf) -> clamped to 90 (matches ref)
__global__ __launch_bounds__(256, 8) void fuzzy_rows(
        const float* __restrict__ maze, float* __restrict__ partial) {
    const int tid  = threadIdx.x;
    const int lane = tid & 63;
    const int wave = tid >> 6;

    // SGPR-uniform row bases: loads compile to saddr form (base in SGPR pair,
    // one shared 32-bit voffset VGPR) -> minimal VGPR addressing cost.
    const float* r0 = maze + (size_t)blockIdx.x * (RPB * MAZE_LEN);
    const float* r1 = r0 + MAZE_LEN;
    const float* r2 = r1 + MAZE_LEN;
    const float* r3 = r2 + MAZE_LEN;

    float a0 = 0.0f, a1 = 0.0f, a2 = 0.0f, a3 = 0.0f;  // one acc per row

    #pragma unroll
    for (int k = 0; k < 4; ++k) {
        const int c  = tid + (k << 8);
        const int cc = (c < NCHUNK) ? c : (NCHUNK - 1);   // in-bounds address
        const int wc = (c < NCHUNK) ? c : 1023;           // zero-weight pad
        const int o  = cc << 2;                           // float offset in row

        // 4 independent row loads + 1 L1-resident table load, no deps between
        // k-slices: up to 16 stream loads in flight per thread.
        const float4 v0 = *(const float4*)(r0 + o);
        const float4 v1 = *(const float4*)(r1 + o);
        const float4 v2 = *(const float4*)(r2 + o);
        const float4 v3 = *(const float4*)(r3 + o);
        const float4 w  = *(const float4*)&c_w.w[wc][0];

        float4 b;
        b.x = (w.x == 0.0f) ? 1e30f : 0.0f;
        b.y = (w.y == 0.0f) ? 1e30f : 0.0f;
        b.z = (w.z == 0.0f) ? 1e30f : 0.0f;
        b.w = (w.w == 0.0f) ? 1e30f : 0.0f;

        a0 = fmaf(w.x, __builtin_amdgcn_rcpf(v0.x + b.x), a0);
        a0 = fmaf(w.y, __builtin_amdgcn_rcpf(v0.y + b.y), a0);
        a0 = fmaf(w.z, __builtin_amdgcn_rcpf(v0.z + b.z), a0);
        a0 = fmaf(w.w, __builtin_amdgcn_rcpf(v0.w + b.w), a0);

        a1 = fmaf(w.x, __builtin_amdgcn_rcpf(v1.x + b.x), a1);
        a1 = fmaf(w.y, __builtin_amdgcn_rcpf(v1.y + b.y), a1);
        a1 = fmaf(w.z, __builtin_amdgcn_rcpf(v1.z + b.z), a1);
        a1 = fmaf(w.w, __builtin_amdgcn_rcpf(v1.w + b.w), a1);

        a2 = fmaf(w.x, __builtin_amdgcn_rcpf(v2.x + b.x), a2);
        a2 = fmaf(w.y, __builtin_amdgcn_rcpf(v2.y + b.y), a2);
        a2 = fmaf(w.z, __builtin_amdgcn_rcpf(v2.z + b.z), a2);
        a2 = fmaf(w.w, __builtin_amdgcn_rcpf(v2.w + b.w), a2);

        a3 = fmaf(w.x, __builtin_amdgcn_rcpf(v3.x + b.x), a3);
        a3 = fmaf(w.y, __builtin_amdgcn_rcpf(v3.y + b.y), a3);
        a3 = fmaf(w.z, __builtin_amdgcn_rcpf(v3.z + b.z), a3);
        a3 = fmaf(w.w, __builtin_amdgcn_rcpf(v3.w + b.w), a3);
    }

    // Single reduction phase, off the load critical path. The 4 chains
    // interleave so the 6-step shuffle latency overlaps across rows.
    #pragma unroll
    for (int off = 32; off > 0; off >>= 1) {
        a0 += __shfl_xor(a0, off, 64);
        a1 += __shfl_xor(a1, off, 64);
        a2 += __shfl_xor(a2, off, 64);
        a3 += __shfl_xor(a3, off, 64);
    }

    __shared__ float s_part[4][RPB];
    __shared__ float s_fin[RPB];
    if (lane == 0) {
        s_part[wave][0] = a0;
        s_part[wave][1] = a1;
        s_part[wave][2] = a2;
        s_part[wave][3] = a3;
    }
    __syncthreads();

    if (tid < RPB) {
        const float S = s_part[0][tid] + s_part[1][tid]
                      + s_part[2][tid] + s_part[3][tid] - NTERMS;
        s_fin[tid] = fminf(log1pf(S), 90.0f);   // inf -> 90 matches ref clamp
    }
    __syncthreads();

    if (tid == 0)
        partial[blockIdx.x] = s_fin[0] + s_fin[1] + s_fin[2] + s_fin[3];
}

// Stage 2: single block folds the 4096 per-block sums into the mean.
__global__ __launch_bounds__(256) void reduce_partials(
        const float* __restrict__ partial, float* __restrict__ out) {
    float t = 0.0f;
    #pragma unroll
    for (int i = 0; i < NBLK1 / 256; ++i)
        t += partial[threadIdx.x + (i << 8)];   // coalesced

    #pragma unroll
    for (int o = 32; o > 0; o >>= 1) t += __shfl_xor(t, o, 64);

    __shared__ float s_part[4];
    if ((threadIdx.x & 63) == 0) s_part[threadIdx.x >> 6] = t;
    __syncthreads();

    if (threadIdx.x == 0)
        out[0] = (s_part[0] + s_part[1] + s_part[2] + s_part[3])
                 * (1.0f / (float)BATCH);
}

extern "C" void kernel_launch(void* const* d_in, const int* in_sizes, int n_in,
                              void* d_out, int out_size, void* d_ws, size_t ws_size,
                              hipStream_t stream) {
    const float* maze = (const float*)d_in[0];
    float* out  = (float*)d_out;
    float* part = (float*)d_ws;   // 4096 floats; fully overwritten by K1 each call

    fuzzy_rows<<<dim3(NBLK1), dim3(256), 0, stream>>>(maze, part);
    reduce_partials<<<dim3(1), dim3(256), 0, stream>>>(part, out);
}

// Round 3
// 297.669 us; speedup vs baseline: 1.1628x; 1.1628x over previous
//
#include <hip/hip_runtime.h>
#include <math.h>

#define BATCH    16384
#define MAZE_LEN 3844
#define NBLOCKS  (BATCH / 4)    // 4 rows per block (1 row per wave), 4096 blocks
#define NTERMS   120.0f         // chain has 120 multiplicands (col 3721 twice)

// Math: with p=0, and_f is additive under u(x)=1/x-1, so per row
//   S = sum_i w_i*(1/x_i) - 120;  -log(clamp(1/(1+S), e^-90)) = min(log1p(S), 90)
//
// R7 structure (model: harness runs the kernel over 4 input copies per timed
// iteration; gather baseline was line-miss-concurrency-bound at ~21 G lines/s).
// The 120 used cols per row live in 3 zones:
//   head:  floats   0..127  (32 chunks, 32 used cols, weights 0..1)
//   tail:  floats 3716..3843 (32 chunks, 32 weight incl. col 3721 w=2)
//   middle: 56 isolated cols {124i+121, 124i+125} i=1..28, weight 1
// Load plan per row (one wave):
//   load1: all 64 lanes float4 -> lanes 0..31 head chunks 0..31,
//          lanes 32..63 tail chunks 929..960  (two coalesced line bursts)
//   load2: lanes 0..55 dword gather of the 56 middle cols (~28 pair-lines)
// Total ~46 lines/row = the irreducible footprint, now issued as 2 sequential
// bursts + 1 small gather instead of two 64-lane scattered gathers.

struct HTab { float w[64][4]; };   // per-lane weight4 for load1 (1 KB)

static constexpr HTab make_h() {
    HTab t{};
    int W[MAZE_LEN] = {};
    W[4 * 1 + 124 * 0 + 2]  += 1;    // IDX_A = 6
    W[4 * 29 + 124 * 30 + 3] += 1;   // IDX_B = 3839
    for (int i = 0; i < 31; ++i) { W[124 * i + 1] += 1; W[124 * i + 121] += 1; }
    for (int i = 0; i < 28; ++i) { W[4 * (i + 2) + 1] += 1; W[4 * i + 3721] += 1; }
    // zone accounting (verified): head w=32, middle w=56, tail w=32 (3721 has w=2)
    for (int lane = 0; lane < 64; ++lane) {
        const int chunk = (lane < 32) ? lane : (929 + (lane - 32));
        for (int j = 0; j < 4; ++j) t.w[lane][j] = (float)W[4 * chunk + j];
    }
    return t;
}

__constant__ HTab c_h = make_h();

// Per load1 element: term = w * rcp(x + B), B = 1e30 iff w==0.
//   unused elem, any x (incl. 0): 0 * 1e-30 = exactly 0 (no 0*inf NaN)
//   used elem, x==0: w * inf -> log1p(inf) -> clamped to 90 (matches ref)
__global__ __launch_bounds__(256) void fuzzy_rows(
        const float* __restrict__ maze, float* __restrict__ partial) {
    const int tid  = threadIdx.x;
    const int lane = tid & 63;
    const int wave = tid >> 6;
    const int row  = (blockIdx.x << 2) | wave;

    const float* rp = maze + (size_t)row * MAZE_LEN;

    // ---- issue both loads up front, independent ----
    // load2: 56-lane middle gather (ascending cols; lanes 56..63 read col 0,
    // result discarded by cndmask so a col-0 zero can't poison the sum)
    const int i    = 1 + (lane >> 1);
    const int mcol = 124 * i + 121 + ((lane & 1) << 2);
    const float xm = rp[(lane < 56) ? mcol : 0];

    // load1: coalesced float4 (head burst for lanes 0..31, tail for 32..63)
    const int chunk = (lane < 32) ? lane : (929 + (lane - 32));
    const float4 v  = *(const float4*)(rp + (chunk << 2));
    const float4 w  = *(const float4*)&c_h.w[lane][0];

    float4 b;
    b.x = (w.x == 0.0f) ? 1e30f : 0.0f;
    b.y = (w.y == 0.0f) ? 1e30f : 0.0f;
    b.z = (w.z == 0.0f) ? 1e30f : 0.0f;
    b.w = (w.w == 0.0f) ? 1e30f : 0.0f;

    float a = fmaf(w.x, __builtin_amdgcn_rcpf(v.x + b.x), 0.0f);
    a = fmaf(w.y, __builtin_amdgcn_rcpf(v.y + b.y), a);
    a = fmaf(w.z, __builtin_amdgcn_rcpf(v.z + b.z), a);
    a = fmaf(w.w, __builtin_amdgcn_rcpf(v.w + b.w), a);
    a += (lane < 56) ? __builtin_amdgcn_rcpf(xm) : 0.0f;  // select, not mul: inf-safe

    #pragma unroll
    for (int off = 32; off > 0; off >>= 1)
        a += __shfl_xor(a, off, 64);

    __shared__ float s_part[4];
    if (lane == 0)
        s_part[wave] = fminf(log1pf(a - NTERMS), 90.0f);  // inf -> 90 matches ref
    __syncthreads();

    if (tid == 0)
        partial[blockIdx.x] = s_part[0] + s_part[1] + s_part[2] + s_part[3];
}

// Stage 2: single block folds the 4096 partials and writes the mean.
__global__ __launch_bounds__(256) void reduce_partials(
        const float* __restrict__ partial, float* __restrict__ out) {
    float t = 0.0f;
    #pragma unroll
    for (int i = 0; i < NBLOCKS / 256; ++i)
        t += partial[threadIdx.x + (i << 8)];   // coalesced

    #pragma unroll
    for (int o = 32; o > 0; o >>= 1) t += __shfl_xor(t, o, 64);

    __shared__ float s_part[4];
    if ((threadIdx.x & 63) == 0) s_part[threadIdx.x >> 6] = t;
    __syncthreads();

    if (threadIdx.x == 0)
        out[0] = (s_part[0] + s_part[1] + s_part[2] + s_part[3])
                 * (1.0f / (float)BATCH);
}

extern "C" void kernel_launch(void* const* d_in, const int* in_sizes, int n_in,
                              void* d_out, int out_size, void* d_ws, size_t ws_size,
                              hipStream_t stream) {
    const float* maze = (const float*)d_in[0];
    float* out  = (float*)d_out;
    float* part = (float*)d_ws;   // 4096 floats; fully overwritten by K1 each call

    fuzzy_rows<<<dim3(NBLOCKS), dim3(256), 0, stream>>>(maze, part);
    reduce_partials<<<dim3(1), dim3(256), 0, stream>>>(part, out);
}